// Round 1
// baseline (641.868 us; speedup 1.0000x reference)
//
#include <hip/hip_runtime.h>

// FastNDCG: per-user first/last occurrence -> 2-element NDCG -> mean.
// ws layout: first[400000] int32 | last[400000] int32 | acc float
static constexpr int NUSERS = 400000;
static constexpr float NEG_INF_F = -1000000000.0f;
static constexpr float INV_LOG2_3 = 0.6309297535714575f; // 1/log2(3)

__global__ void k_init(int* __restrict__ first, int* __restrict__ last,
                       float* __restrict__ acc) {
    int i = blockIdx.x * blockDim.x + threadIdx.x;
    if (i < NUSERS) { first[i] = 0x7FFFFFFF; last[i] = -1; }
    if (i == 0) acc[0] = 0.0f;
}

__global__ void k_minmax(const int* __restrict__ idx, int* __restrict__ first,
                         int* __restrict__ last, int n) {
    int base = (blockIdx.x * blockDim.x + threadIdx.x) * 4;
    if (base + 3 < n) {
        int4 u4 = *reinterpret_cast<const int4*>(idx + base);
        int us[4] = {u4.x, u4.y, u4.z, u4.w};
#pragma unroll
        for (int j = 0; j < 4; ++j) {
            int u = us[j];
            int i = base + j;
            // Racy pre-check is safe: first[] only ever decreases, last[] only
            // ever increases, so a stale read can only cause a redundant atomic
            // or skip an atomic that would have been a no-op.
            if (i < first[u]) atomicMin(&first[u], i);
            if (i > last[u])  atomicMax(&last[u], i);
        }
    } else {
        for (int i = base; i < n; ++i) {
            int u = idx[i];
            if (i < first[u]) atomicMin(&first[u], i);
            if (i > last[u])  atomicMax(&last[u], i);
        }
    }
}

__global__ void k_ndcg(const float* __restrict__ pred, const float* __restrict__ tgt,
                       const int* __restrict__ first, const int* __restrict__ last,
                       int n, float* __restrict__ acc) {
    int u = blockIdx.x * blockDim.x + threadIdx.x;
    float v = 0.0f;
    if (u < NUSERS) {
        int f = first[u];
        int l = last[u];
        f = min(f, n - 1);      // count==0: segment_min identity INT_MAX, jax clamps gather
        float p0 = pred[f];
        float t0 = tgt[f];
        bool has2 = l > f;      // count>=2 <=> distinct first/last positions
        float p1 = has2 ? pred[l] : NEG_INF_F;
        float t1 = has2 ? tgt[l] : 0.0f;
        // top_k tie-break: lower index wins -> p0 >= p1 puts t0 first
        float dcg  = (p0 >= p1) ? fmaf(t1, INV_LOG2_3, t0) : fmaf(t0, INV_LOG2_3, t1);
        float idcg = fmaf(fminf(t0, t1), INV_LOG2_3, fmaxf(t0, t1));
        v = dcg / idcg;         // 0/0 -> NaN matches reference semantics
    }
    // wave64 shuffle reduce
    for (int off = 32; off > 0; off >>= 1) v += __shfl_down(v, off, 64);
    __shared__ float wsum[4];
    int lane = threadIdx.x & 63;
    int wid = threadIdx.x >> 6;
    if (lane == 0) wsum[wid] = v;
    __syncthreads();
    if (threadIdx.x == 0) {
        atomicAdd(acc, wsum[0] + wsum[1] + wsum[2] + wsum[3]);
    }
}

__global__ void k_final(const float* __restrict__ acc, float* __restrict__ out) {
    out[0] = acc[0] * (1.0f / (float)NUSERS);
}

extern "C" void kernel_launch(void* const* d_in, const int* in_sizes, int n_in,
                              void* d_out, int out_size, void* d_ws, size_t ws_size,
                              hipStream_t stream) {
    const float* pred = (const float*)d_in[0];
    const float* tgt  = (const float*)d_in[1];
    const int*   idx  = (const int*)d_in[2];
    const int n = in_sizes[0];

    int* first = (int*)d_ws;
    int* last  = first + NUSERS;
    float* acc = (float*)(last + NUSERS);
    float* out = (float*)d_out;

    k_init<<<(NUSERS + 255) / 256, 256, 0, stream>>>(first, last, acc);

    int nq = (n + 3) / 4;
    k_minmax<<<(nq + 255) / 256, 256, 0, stream>>>(idx, first, last, n);

    k_ndcg<<<(NUSERS + 255) / 256, 256, 0, stream>>>(pred, tgt, first, last, n, acc);

    k_final<<<1, 1, 0, stream>>>(acc, out);
}